// Round 8
// baseline (705.559 us; speedup 1.0000x reference)
//
#include <hip/hip_runtime.h>
#include <hip/hip_bf16.h>
#include <math.h>

#define LEAKY 0.2f

// ---------------- fp32 tiled GEMM + fused attention scores ----------------
// C[M,NC] = A[M,K] @ B[K,NC]; asrc[n,h] = sum_c C[n,h*64+c]*att_s[h*64+c] (same for adst).
// Works because BN=64 == head width: blockIdx.y <-> head, no cross-block reduction.
#define BM 64
#define BN 64
#define BK 32
__global__ __launch_bounds__(256) void gemm_att(const float* __restrict__ A,
                                                const float* __restrict__ B,
                                                float* __restrict__ C,
                                                const float* __restrict__ att_s,
                                                const float* __restrict__ att_d,
                                                float* __restrict__ asrc,
                                                float* __restrict__ adst,
                                                int M, int K, int NC) {
    __shared__ float As[BK][BM + 1];
    __shared__ float Bs[BK][BN];
    const int tid = threadIdx.x;
    const int bm = blockIdx.x * BM;
    const int bn = blockIdx.y * BN;
    const int tx = tid & 15, ty = tid >> 4;
    float acc[4][4] = {};
    for (int k0 = 0; k0 < K; k0 += BK) {
        #pragma unroll
        for (int i = 0; i < (BM * BK) / 256; ++i) {
            int idx = tid + i * 256;
            int r = idx >> 5, c = idx & 31;
            int gr = bm + r;
            As[c][r] = (gr < M) ? A[(size_t)gr * K + k0 + c] : 0.f;
        }
        #pragma unroll
        for (int i = 0; i < (BK * BN) / 256; ++i) {
            int idx = tid + i * 256;
            int r = idx >> 6, c = idx & 63;
            Bs[r][c] = B[(size_t)(k0 + r) * NC + bn + c];
        }
        __syncthreads();
        #pragma unroll
        for (int k = 0; k < BK; ++k) {
            float a[4], b[4];
            #pragma unroll
            for (int i = 0; i < 4; ++i) a[i] = As[k][ty * 4 + i];
            #pragma unroll
            for (int j = 0; j < 4; ++j) b[j] = Bs[k][tx * 4 + j];
            #pragma unroll
            for (int i = 0; i < 4; ++i)
                #pragma unroll
                for (int j = 0; j < 4; ++j)
                    acc[i][j] += a[i] * b[j];
        }
        __syncthreads();
    }
    // att vectors for this block's 64-wide column slice (= one head)
    float s_att[4], d_att[4];
    #pragma unroll
    for (int j = 0; j < 4; ++j) {
        s_att[j] = att_s[bn + tx * 4 + j];
        d_att[j] = att_d[bn + tx * 4 + j];
    }
    const int head = bn >> 6;
    const int H = NC >> 6;
    #pragma unroll
    for (int i = 0; i < 4; ++i) {
        int gr = bm + ty * 4 + i;
        float ps = 0.f, pd = 0.f;
        #pragma unroll
        for (int j = 0; j < 4; ++j) {
            ps += acc[i][j] * s_att[j];
            pd += acc[i][j] * d_att[j];
        }
        // reduce across the 16 tx-lanes (lane bits 0..3)
        #pragma unroll
        for (int o = 1; o < 16; o <<= 1) {
            ps += __shfl_xor(ps, o);
            pd += __shfl_xor(pd, o);
        }
        if (gr < M) {
            #pragma unroll
            for (int j = 0; j < 4; ++j)
                C[(size_t)gr * NC + bn + tx * 4 + j] = acc[i][j];
            if (tx == 0) {
                asrc[gr * H + head] = ps;
                adst[gr * H + head] = pd;
            }
        }
    }
}

// ---------------- CSR build ----------------
__global__ __launch_bounds__(256) void count_deg(const int* __restrict__ ei, int E_, int N_,
                                                 int* __restrict__ deg) {
    int eid = blockIdx.x * 256 + threadIdx.x;
    int Etot = E_ + N_;
    if (eid >= Etot) return;
    int dst = (eid < E_) ? ei[E_ + eid] : (eid - E_);
    atomicAdd(&deg[dst], 1);
}

// single block, 1024 threads: off = exclusive_scan(deg), off[n] = total
__global__ __launch_bounds__(1024) void scan_offsets(const int* __restrict__ deg,
                                                     int* __restrict__ off, int n) {
    __shared__ int wsum[16];
    int tid = threadIdx.x;
    int lane = tid & 63, w = tid >> 6;
    int chunk = (n + 1023) / 1024;
    int b = tid * chunk;
    int e = min(b + chunk, n);
    int s = 0;
    for (int i = b; i < e; ++i) s += deg[i];
    int v = s;
    #pragma unroll
    for (int o = 1; o < 64; o <<= 1) {
        int t = __shfl_up(v, o);
        if (lane >= o) v += t;
    }
    if (lane == 63) wsum[w] = v;
    __syncthreads();
    if (w == 0) {
        int t = (lane < 16) ? wsum[lane] : 0;
        #pragma unroll
        for (int o = 1; o < 16; o <<= 1) {
            int u = __shfl_up(t, o);
            if (lane >= o) t += u;
        }
        if (lane < 16) wsum[lane] = t;
    }
    __syncthreads();
    int acc = (w > 0 ? wsum[w - 1] : 0) + (v - s);   // exclusive prefix for this thread
    for (int i = b; i < e; ++i) { off[i] = acc; acc += deg[i]; }
    if (e == n) off[n] = acc;   // all tail threads write the same total
}

// scatter src ids into buckets; uses off[] as in-place cursor.
// post: off[d] = end of bucket d (start = off[d-1], or 0 for d==0)
__global__ __launch_bounds__(256) void scatter_edges(const int* __restrict__ ei, int E_, int N_,
                                                     int* __restrict__ off,
                                                     int* __restrict__ csr) {
    int eid = blockIdx.x * 256 + threadIdx.x;
    int Etot = E_ + N_;
    if (eid >= Etot) return;
    int src, dst;
    if (eid < E_) { src = ei[eid]; dst = ei[E_ + eid]; }
    else          { src = dst = eid - E_; }
    int pos = atomicAdd(&off[dst], 1);
    csr[pos] = src;
}

// ---------------- fused GAT aggregation, 4 heads: block per node, wave per head ----------------
__global__ __launch_bounds__(256) void gat_agg_h4(const int* __restrict__ off,
                                                  const int* __restrict__ csr,
                                                  const float* __restrict__ asrc,
                                                  const float* __restrict__ adst,
                                                  const float* __restrict__ hsrc,
                                                  const float* __restrict__ bias,
                                                  float* __restrict__ outp, int N_) {
    int head = threadIdx.x >> 6;      // wave index = head
    int lane = threadIdx.x & 63;
    int node = blockIdx.x;
    if (node >= N_) return;
    int s = node ? off[node - 1] : 0;
    int e = off[node];
    float ad = adst[node * 4 + head];
    // pass 1: lane-parallel segment max for this head
    float m = -INFINITY;
    for (int i = s + lane; i < e; i += 64) {
        float ev = asrc[csr[i] * 4 + head] + ad;
        ev = ev > 0.f ? ev : LEAKY * ev;
        m = fmaxf(m, ev);
    }
    #pragma unroll
    for (int o = 32; o > 0; o >>= 1) m = fmaxf(m, __shfl_xor(m, o));
    // pass 2: serial over edges; 1 exp + 1 fma + 256B gather per edge
    float a = 0.f, d = 0.f;
    for (int i = s; i < e; ++i) {
        int u = csr[i];
        float ev = asrc[u * 4 + head] + ad;
        ev = ev > 0.f ? ev : LEAKY * ev;
        float w = __expf(ev - m);
        d += w;
        a += w * hsrc[(size_t)u * 256 + head * 64 + lane];
    }
    float v = a / (d + 1e-16f) + bias[head * 64 + lane];
    outp[(size_t)node * 256 + head * 64 + lane] = v > 0.f ? v : expm1f(v);
}

// ---------------- fused GAT aggregation, 1 head x 64 ch (wave per node) ----------------
__global__ __launch_bounds__(256) void gat_agg_h1(const int* __restrict__ off,
                                                  const int* __restrict__ csr,
                                                  const float* __restrict__ asrc,
                                                  const float* __restrict__ adst,
                                                  const float* __restrict__ g,
                                                  const float* __restrict__ bias,
                                                  float* __restrict__ outp, int N_) {
    int wv = threadIdx.x >> 6, lane = threadIdx.x & 63;
    int node = blockIdx.x * 4 + wv;
    if (node >= N_) return;
    int s = node ? off[node - 1] : 0;
    int e = off[node];
    float ad = adst[node];
    float mm = -INFINITY;
    for (int i = s + lane; i < e; i += 64) {
        float ev = asrc[csr[i]] + ad;
        ev = ev > 0.f ? ev : LEAKY * ev;
        mm = fmaxf(mm, ev);
    }
    #pragma unroll
    for (int o = 32; o > 0; o >>= 1) mm = fmaxf(mm, __shfl_xor(mm, o));
    float a = 0.f, d = 0.f;
    for (int i = s; i < e; ++i) {
        int u = csr[i];
        float ev = asrc[u] + ad;
        ev = ev > 0.f ? ev : LEAKY * ev;
        float w = __expf(ev - mm);
        d += w;
        a += w * g[(size_t)u * 64 + lane];
    }
    float v = a / (d + 1e-16f) + bias[lane];
    outp[(size_t)node * 64 + lane] = v > 0.f ? v : expm1f(v);
}

extern "C" void kernel_launch(void* const* d_in, const int* in_sizes, int n_in,
                              void* d_out, int out_size, void* d_ws, size_t ws_size,
                              hipStream_t stream) {
    const float* x        = (const float*)d_in[0];
    const int*   ei       = (const int*)d_in[1];     // int32 (harness: integer -> const int*)
    // d_in[2] = edge_attr (unused: PyG GATConv with edge_dim=None)
    const float* W1       = (const float*)d_in[3];
    const float* att_src1 = (const float*)d_in[4];
    const float* att_dst1 = (const float*)d_in[5];
    const float* b1       = (const float*)d_in[6];
    const float* W2       = (const float*)d_in[7];
    const float* att_src2 = (const float*)d_in[8];
    const float* att_dst2 = (const float*)d_in[9];
    const float* b2       = (const float*)d_in[10];
    float* out = (float*)d_out;

    const int N = in_sizes[0] / 128;     // 50000
    const int E = in_sizes[1] / 2;       // 800000
    const int Etot = E + N;

    float* ws    = (float*)d_ws;
    float* h1    = ws;                         // N*256  (L1 GEMM out; dead after gat_agg_h4)
    float* h2    = h1 + (size_t)N * 256;       // N*256  (L1 out = L2 GEMM in)
    float* g2    = h1;                         // N*64   (aliases h1 — dead by then)
    float* asrc1 = h2 + (size_t)N * 256;       // N*4
    float* adst1 = asrc1 + (size_t)N * 4;      // N*4
    float* asrc2 = adst1 + (size_t)N * 4;      // N
    float* adst2 = asrc2 + N;                  // N
    int*   deg   = (int*)(adst2 + N);          // N+1
    int*   off   = deg + (N + 1);              // N+1 (scan out; scatter cursor; bucket ends)
    int*   csr   = off + (N + 1);              // Etot

    // ---- CSR build (graph identical for both layers) ----
    hipMemsetAsync(deg, 0, (N + 1) * sizeof(int), stream);
    count_deg<<<(Etot + 255) / 256, 256, 0, stream>>>(ei, E, N, deg);
    scan_offsets<<<1, 1024, 0, stream>>>(deg, off, N);
    scatter_edges<<<(Etot + 255) / 256, 256, 0, stream>>>(ei, E, N, off, csr);

    // ---- layer 1 ----
    {
        dim3 g((N + BM - 1) / BM, 256 / BN);
        gemm_att<<<g, 256, 0, stream>>>(x, W1, h1, att_src1, att_dst1, asrc1, adst1, N, 128, 256);
    }
    gat_agg_h4<<<N, 256, 0, stream>>>(off, csr, asrc1, adst1, h1, b1, h2, N);

    // ---- layer 2 ----
    {
        dim3 g((N + BM - 1) / BM, 64 / BN);
        gemm_att<<<g, 256, 0, stream>>>(h2, W2, g2, att_src2, att_dst2, asrc2, adst2, N, 256, 64);
    }
    gat_agg_h1<<<(N + 3) / 4, 256, 0, stream>>>(off, csr, asrc2, adst2, g2, b2, out, N);
}

// Round 9
// 581.015 us; speedup vs baseline: 1.2144x; 1.2144x over previous
//
#include <hip/hip_runtime.h>
#include <hip/hip_bf16.h>
#include <math.h>

#define LEAKY 0.2f

// ---------------- fp32 tiled GEMM + fused attention scores ----------------
// C[M,NC] = A[M,K] @ B[K,NC]; asrc[n,h] = sum_c C[n,h*64+c]*att_s[h*64+c] (same for adst).
// Works because BN=64 == head width: blockIdx.y <-> head, no cross-block reduction.
#define BM 64
#define BN 64
#define BK 32
__global__ __launch_bounds__(256) void gemm_att(const float* __restrict__ A,
                                                const float* __restrict__ B,
                                                float* __restrict__ C,
                                                const float* __restrict__ att_s,
                                                const float* __restrict__ att_d,
                                                float* __restrict__ asrc,
                                                float* __restrict__ adst,
                                                int M, int K, int NC) {
    __shared__ float As[BK][BM + 1];
    __shared__ float Bs[BK][BN];
    const int tid = threadIdx.x;
    const int bm = blockIdx.x * BM;
    const int bn = blockIdx.y * BN;
    const int tx = tid & 15, ty = tid >> 4;
    float acc[4][4] = {};
    for (int k0 = 0; k0 < K; k0 += BK) {
        #pragma unroll
        for (int i = 0; i < (BM * BK) / 256; ++i) {
            int idx = tid + i * 256;
            int r = idx >> 5, c = idx & 31;
            int gr = bm + r;
            As[c][r] = (gr < M) ? A[(size_t)gr * K + k0 + c] : 0.f;
        }
        #pragma unroll
        for (int i = 0; i < (BK * BN) / 256; ++i) {
            int idx = tid + i * 256;
            int r = idx >> 6, c = idx & 63;
            Bs[r][c] = B[(size_t)(k0 + r) * NC + bn + c];
        }
        __syncthreads();
        #pragma unroll
        for (int k = 0; k < BK; ++k) {
            float a[4], b[4];
            #pragma unroll
            for (int i = 0; i < 4; ++i) a[i] = As[k][ty * 4 + i];
            #pragma unroll
            for (int j = 0; j < 4; ++j) b[j] = Bs[k][tx * 4 + j];
            #pragma unroll
            for (int i = 0; i < 4; ++i)
                #pragma unroll
                for (int j = 0; j < 4; ++j)
                    acc[i][j] += a[i] * b[j];
        }
        __syncthreads();
    }
    // att vectors for this block's 64-wide column slice (= one head)
    float s_att[4], d_att[4];
    #pragma unroll
    for (int j = 0; j < 4; ++j) {
        s_att[j] = att_s[bn + tx * 4 + j];
        d_att[j] = att_d[bn + tx * 4 + j];
    }
    const int head = bn >> 6;
    const int H = NC >> 6;
    #pragma unroll
    for (int i = 0; i < 4; ++i) {
        int gr = bm + ty * 4 + i;
        float ps = 0.f, pd = 0.f;
        #pragma unroll
        for (int j = 0; j < 4; ++j) {
            ps += acc[i][j] * s_att[j];
            pd += acc[i][j] * d_att[j];
        }
        // reduce across the 16 tx-lanes (lane bits 0..3)
        #pragma unroll
        for (int o = 1; o < 16; o <<= 1) {
            ps += __shfl_xor(ps, o);
            pd += __shfl_xor(pd, o);
        }
        if (gr < M) {
            #pragma unroll
            for (int j = 0; j < 4; ++j)
                C[(size_t)gr * NC + bn + tx * 4 + j] = acc[i][j];
            if (tx == 0) {
                asrc[gr * H + head] = ps;
                adst[gr * H + head] = pd;
            }
        }
    }
}

// ---------------- CSR build ----------------
__global__ __launch_bounds__(256) void count_deg(const int* __restrict__ ei, int E_, int N_,
                                                 int* __restrict__ deg) {
    int eid = blockIdx.x * 256 + threadIdx.x;
    int Etot = E_ + N_;
    if (eid >= Etot) return;
    int dst = (eid < E_) ? ei[E_ + eid] : (eid - E_);
    atomicAdd(&deg[dst], 1);
}

// single block, 1024 threads: off = exclusive_scan(deg), off[n] = total
__global__ __launch_bounds__(1024) void scan_offsets(const int* __restrict__ deg,
                                                     int* __restrict__ off, int n) {
    __shared__ int wsum[16];
    int tid = threadIdx.x;
    int lane = tid & 63, w = tid >> 6;
    int chunk = (n + 1023) / 1024;
    int b = tid * chunk;
    int e = min(b + chunk, n);
    int s = 0;
    for (int i = b; i < e; ++i) s += deg[i];
    int v = s;
    #pragma unroll
    for (int o = 1; o < 64; o <<= 1) {
        int t = __shfl_up(v, o);
        if (lane >= o) v += t;
    }
    if (lane == 63) wsum[w] = v;
    __syncthreads();
    if (w == 0) {
        int t = (lane < 16) ? wsum[lane] : 0;
        #pragma unroll
        for (int o = 1; o < 16; o <<= 1) {
            int u = __shfl_up(t, o);
            if (lane >= o) t += u;
        }
        if (lane < 16) wsum[lane] = t;
    }
    __syncthreads();
    int acc = (w > 0 ? wsum[w - 1] : 0) + (v - s);   // exclusive prefix for this thread
    for (int i = b; i < e; ++i) { off[i] = acc; acc += deg[i]; }
    if (e == n) off[n] = acc;   // all tail threads write the same total
}

// scatter src ids into buckets; uses off[] as in-place cursor.
// post: off[d] = end of bucket d (start = off[d-1], or 0 for d==0)
__global__ __launch_bounds__(256) void scatter_edges(const int* __restrict__ ei, int E_, int N_,
                                                     int* __restrict__ off,
                                                     int* __restrict__ csr) {
    int eid = blockIdx.x * 256 + threadIdx.x;
    int Etot = E_ + N_;
    if (eid >= Etot) return;
    int src, dst;
    if (eid < E_) { src = ei[eid]; dst = ei[E_ + eid]; }
    else          { src = dst = eid - E_; }
    int pos = atomicAdd(&off[dst], 1);
    csr[pos] = src;
}

// ---------------- fused GAT aggregation, 4 heads x 64 ch (wave per node, unroll 2) ----------------
__global__ __launch_bounds__(256) void gat_agg_h4(const int* __restrict__ off,
                                                  const int* __restrict__ csr,
                                                  const float* __restrict__ asrc,
                                                  const float* __restrict__ adst,
                                                  const float* __restrict__ hsrc,
                                                  const float* __restrict__ bias,
                                                  float* __restrict__ outp, int N_) {
    int wv = threadIdx.x >> 6, lane = threadIdx.x & 63;
    int node = blockIdx.x * 4 + wv;
    if (node >= N_) return;
    int s = node ? off[node - 1] : 0;
    int e = off[node];
    float4 ad = *(const float4*)(adst + node * 4);
    // pass 1: segment max (lane-parallel over edges)
    float m0 = -INFINITY, m1 = -INFINITY, m2 = -INFINITY, m3 = -INFINITY;
    for (int i = s + lane; i < e; i += 64) {
        int u = csr[i];
        float4 as = *(const float4*)(asrc + u * 4);
        float e0 = as.x + ad.x; e0 = e0 > 0.f ? e0 : LEAKY * e0; m0 = fmaxf(m0, e0);
        float e1 = as.y + ad.y; e1 = e1 > 0.f ? e1 : LEAKY * e1; m1 = fmaxf(m1, e1);
        float e2 = as.z + ad.z; e2 = e2 > 0.f ? e2 : LEAKY * e2; m2 = fmaxf(m2, e2);
        float e3 = as.w + ad.w; e3 = e3 > 0.f ? e3 : LEAKY * e3; m3 = fmaxf(m3, e3);
    }
    #pragma unroll
    for (int o = 32; o > 0; o >>= 1) {
        m0 = fmaxf(m0, __shfl_xor(m0, o));
        m1 = fmaxf(m1, __shfl_xor(m1, o));
        m2 = fmaxf(m2, __shfl_xor(m2, o));
        m3 = fmaxf(m3, __shfl_xor(m3, o));
    }
    // pass 2: unroll x2 -> 8 independent 256B gathers in flight per iteration
    float a0 = 0.f, a1 = 0.f, a2 = 0.f, a3 = 0.f;
    float d0 = 0.f, d1 = 0.f, d2 = 0.f, d3 = 0.f;
    int i = s;
    for (; i + 2 <= e; i += 2) {
        int u0 = csr[i], u1 = csr[i + 1];
        float4 as0 = *(const float4*)(asrc + u0 * 4);
        float4 as1 = *(const float4*)(asrc + u1 * 4);
        const float* hp0 = hsrc + (size_t)u0 * 256 + lane;
        const float* hp1 = hsrc + (size_t)u1 * 256 + lane;
        float g00 = hp0[0], g01 = hp0[64], g02 = hp0[128], g03 = hp0[192];
        float g10 = hp1[0], g11 = hp1[64], g12 = hp1[128], g13 = hp1[192];
        float ev, w;
        ev = as0.x + ad.x; ev = ev > 0.f ? ev : LEAKY * ev; w = __expf(ev - m0); d0 += w; a0 += w * g00;
        ev = as0.y + ad.y; ev = ev > 0.f ? ev : LEAKY * ev; w = __expf(ev - m1); d1 += w; a1 += w * g01;
        ev = as0.z + ad.z; ev = ev > 0.f ? ev : LEAKY * ev; w = __expf(ev - m2); d2 += w; a2 += w * g02;
        ev = as0.w + ad.w; ev = ev > 0.f ? ev : LEAKY * ev; w = __expf(ev - m3); d3 += w; a3 += w * g03;
        ev = as1.x + ad.x; ev = ev > 0.f ? ev : LEAKY * ev; w = __expf(ev - m0); d0 += w; a0 += w * g10;
        ev = as1.y + ad.y; ev = ev > 0.f ? ev : LEAKY * ev; w = __expf(ev - m1); d1 += w; a1 += w * g11;
        ev = as1.z + ad.z; ev = ev > 0.f ? ev : LEAKY * ev; w = __expf(ev - m2); d2 += w; a2 += w * g12;
        ev = as1.w + ad.w; ev = ev > 0.f ? ev : LEAKY * ev; w = __expf(ev - m3); d3 += w; a3 += w * g13;
    }
    if (i < e) {
        int u = csr[i];
        float4 as = *(const float4*)(asrc + u * 4);
        const float* hp = hsrc + (size_t)u * 256 + lane;
        float g0 = hp[0], g1 = hp[64], g2 = hp[128], g3 = hp[192];
        float ev, w;
        ev = as.x + ad.x; ev = ev > 0.f ? ev : LEAKY * ev; w = __expf(ev - m0); d0 += w; a0 += w * g0;
        ev = as.y + ad.y; ev = ev > 0.f ? ev : LEAKY * ev; w = __expf(ev - m1); d1 += w; a1 += w * g1;
        ev = as.z + ad.z; ev = ev > 0.f ? ev : LEAKY * ev; w = __expf(ev - m2); d2 += w; a2 += w * g2;
        ev = as.w + ad.w; ev = ev > 0.f ? ev : LEAKY * ev; w = __expf(ev - m3); d3 += w; a3 += w * g3;
    }
    size_t ob = (size_t)node * 256 + lane;
    float v;
    v = a0 / (d0 + 1e-16f) + bias[lane];       outp[ob]       = v > 0.f ? v : expm1f(v);
    v = a1 / (d1 + 1e-16f) + bias[lane + 64];  outp[ob + 64]  = v > 0.f ? v : expm1f(v);
    v = a2 / (d2 + 1e-16f) + bias[lane + 128]; outp[ob + 128] = v > 0.f ? v : expm1f(v);
    v = a3 / (d3 + 1e-16f) + bias[lane + 192]; outp[ob + 192] = v > 0.f ? v : expm1f(v);
}

// ---------------- fused GAT aggregation, 1 head x 64 ch (wave per node, unroll 4) ----------------
__global__ __launch_bounds__(256) void gat_agg_h1(const int* __restrict__ off,
                                                  const int* __restrict__ csr,
                                                  const float* __restrict__ asrc,
                                                  const float* __restrict__ adst,
                                                  const float* __restrict__ g,
                                                  const float* __restrict__ bias,
                                                  float* __restrict__ outp, int N_) {
    int wv = threadIdx.x >> 6, lane = threadIdx.x & 63;
    int node = blockIdx.x * 4 + wv;
    if (node >= N_) return;
    int s = node ? off[node - 1] : 0;
    int e = off[node];
    float ad = adst[node];
    float mm = -INFINITY;
    for (int i = s + lane; i < e; i += 64) {
        float ev = asrc[csr[i]] + ad;
        ev = ev > 0.f ? ev : LEAKY * ev;
        mm = fmaxf(mm, ev);
    }
    #pragma unroll
    for (int o = 32; o > 0; o >>= 1) mm = fmaxf(mm, __shfl_xor(mm, o));
    float a = 0.f, d = 0.f;
    int i = s;
    for (; i + 4 <= e; i += 4) {
        int u0 = csr[i], u1 = csr[i + 1], u2 = csr[i + 2], u3 = csr[i + 3];
        float s0 = asrc[u0], s1 = asrc[u1], s2 = asrc[u2], s3 = asrc[u3];
        float g0 = g[(size_t)u0 * 64 + lane];
        float g1 = g[(size_t)u1 * 64 + lane];
        float g2 = g[(size_t)u2 * 64 + lane];
        float g3 = g[(size_t)u3 * 64 + lane];
        float ev, w;
        ev = s0 + ad; ev = ev > 0.f ? ev : LEAKY * ev; w = __expf(ev - mm); d += w; a += w * g0;
        ev = s1 + ad; ev = ev > 0.f ? ev : LEAKY * ev; w = __expf(ev - mm); d += w; a += w * g1;
        ev = s2 + ad; ev = ev > 0.f ? ev : LEAKY * ev; w = __expf(ev - mm); d += w; a += w * g2;
        ev = s3 + ad; ev = ev > 0.f ? ev : LEAKY * ev; w = __expf(ev - mm); d += w; a += w * g3;
    }
    for (; i < e; ++i) {
        int u = csr[i];
        float ev = asrc[u] + ad;
        ev = ev > 0.f ? ev : LEAKY * ev;
        float w = __expf(ev - mm);
        d += w;
        a += w * g[(size_t)u * 64 + lane];
    }
    float v = a / (d + 1e-16f) + bias[lane];
    outp[(size_t)node * 64 + lane] = v > 0.f ? v : expm1f(v);
}

extern "C" void kernel_launch(void* const* d_in, const int* in_sizes, int n_in,
                              void* d_out, int out_size, void* d_ws, size_t ws_size,
                              hipStream_t stream) {
    const float* x        = (const float*)d_in[0];
    const int*   ei       = (const int*)d_in[1];     // int32 (harness: integer -> const int*)
    // d_in[2] = edge_attr (unused: PyG GATConv with edge_dim=None)
    const float* W1       = (const float*)d_in[3];
    const float* att_src1 = (const float*)d_in[4];
    const float* att_dst1 = (const float*)d_in[5];
    const float* b1       = (const float*)d_in[6];
    const float* W2       = (const float*)d_in[7];
    const float* att_src2 = (const float*)d_in[8];
    const float* att_dst2 = (const float*)d_in[9];
    const float* b2       = (const float*)d_in[10];
    float* out = (float*)d_out;

    const int N = in_sizes[0] / 128;     // 50000
    const int E = in_sizes[1] / 2;       // 800000
    const int Etot = E + N;

    float* ws    = (float*)d_ws;
    float* h1    = ws;                         // N*256  (L1 GEMM out; dead after gat_agg_h4)
    float* h2    = h1 + (size_t)N * 256;       // N*256  (L1 out = L2 GEMM in)
    float* g2    = h1;                         // N*64   (aliases h1 — dead by then)
    float* asrc1 = h2 + (size_t)N * 256;       // N*4
    float* adst1 = asrc1 + (size_t)N * 4;      // N*4
    float* asrc2 = adst1 + (size_t)N * 4;      // N
    float* adst2 = asrc2 + N;                  // N
    int*   deg   = (int*)(adst2 + N);          // N+1
    int*   off   = deg + (N + 1);              // N+1 (scan out; scatter cursor; bucket ends)
    int*   csr   = off + (N + 1);              // Etot

    // ---- CSR build (graph identical for both layers) ----
    hipMemsetAsync(deg, 0, (N + 1) * sizeof(int), stream);
    count_deg<<<(Etot + 255) / 256, 256, 0, stream>>>(ei, E, N, deg);
    scan_offsets<<<1, 1024, 0, stream>>>(deg, off, N);
    scatter_edges<<<(Etot + 255) / 256, 256, 0, stream>>>(ei, E, N, off, csr);

    // ---- layer 1 ----
    {
        dim3 g((N + BM - 1) / BM, 256 / BN);
        gemm_att<<<g, 256, 0, stream>>>(x, W1, h1, att_src1, att_dst1, asrc1, adst1, N, 128, 256);
    }
    gat_agg_h4<<<(N + 3) / 4, 256, 0, stream>>>(off, csr, asrc1, adst1, h1, b1, h2, N);

    // ---- layer 2 ----
    {
        dim3 g((N + BM - 1) / BM, 64 / BN);
        gemm_att<<<g, 256, 0, stream>>>(h2, W2, g2, att_src2, att_dst2, asrc2, adst2, N, 256, 64);
    }
    gat_agg_h1<<<(N + 3) / 4, 256, 0, stream>>>(off, csr, asrc2, adst2, g2, b2, out, N);
}

// Round 11
// 573.947 us; speedup vs baseline: 1.2293x; 1.0123x over previous
//
#include <hip/hip_runtime.h>
#include <hip/hip_bf16.h>
#include <math.h>

#define LEAKY 0.2f

// ---------------- fp32 tiled GEMM + fused attention scores ----------------
// C[M,NC] = A[M,K] @ B[K,NC]; asrc[n,h] = sum_c C[n,h*64+c]*att_s[h*64+c] (same for adst).
// Works because BN=64 == head width: blockIdx.y <-> head, no cross-block reduction.
#define BM 64
#define BN 64
#define BK 32
__global__ __launch_bounds__(256) void gemm_att(const float* __restrict__ A,
                                                const float* __restrict__ B,
                                                float* __restrict__ C,
                                                const float* __restrict__ att_s,
                                                const float* __restrict__ att_d,
                                                float* __restrict__ asrc,
                                                float* __restrict__ adst,
                                                int M, int K, int NC) {
    __shared__ float As[BK][BM + 1];
    __shared__ float Bs[BK][BN];
    const int tid = threadIdx.x;
    const int bm = blockIdx.x * BM;
    const int bn = blockIdx.y * BN;
    const int tx = tid & 15, ty = tid >> 4;
    float acc[4][4] = {};
    for (int k0 = 0; k0 < K; k0 += BK) {
        #pragma unroll
        for (int i = 0; i < (BM * BK) / 256; ++i) {
            int idx = tid + i * 256;
            int r = idx >> 5, c = idx & 31;
            int gr = bm + r;
            As[c][r] = (gr < M) ? A[(size_t)gr * K + k0 + c] : 0.f;
        }
        #pragma unroll
        for (int i = 0; i < (BK * BN) / 256; ++i) {
            int idx = tid + i * 256;
            int r = idx >> 6, c = idx & 63;
            Bs[r][c] = B[(size_t)(k0 + r) * NC + bn + c];
        }
        __syncthreads();
        #pragma unroll
        for (int k = 0; k < BK; ++k) {
            float a[4], b[4];
            #pragma unroll
            for (int i = 0; i < 4; ++i) a[i] = As[k][ty * 4 + i];
            #pragma unroll
            for (int j = 0; j < 4; ++j) b[j] = Bs[k][tx * 4 + j];
            #pragma unroll
            for (int i = 0; i < 4; ++i)
                #pragma unroll
                for (int j = 0; j < 4; ++j)
                    acc[i][j] += a[i] * b[j];
        }
        __syncthreads();
    }
    float s_att[4], d_att[4];
    #pragma unroll
    for (int j = 0; j < 4; ++j) {
        s_att[j] = att_s[bn + tx * 4 + j];
        d_att[j] = att_d[bn + tx * 4 + j];
    }
    const int head = bn >> 6;
    const int H = NC >> 6;
    #pragma unroll
    for (int i = 0; i < 4; ++i) {
        int gr = bm + ty * 4 + i;
        float ps = 0.f, pd = 0.f;
        #pragma unroll
        for (int j = 0; j < 4; ++j) {
            ps += acc[i][j] * s_att[j];
            pd += acc[i][j] * d_att[j];
        }
        #pragma unroll
        for (int o = 1; o < 16; o <<= 1) {
            ps += __shfl_xor(ps, o);
            pd += __shfl_xor(pd, o);
        }
        if (gr < M) {
            #pragma unroll
            for (int j = 0; j < 4; ++j)
                C[(size_t)gr * NC + bn + tx * 4 + j] = acc[i][j];
            if (tx == 0) {
                asrc[gr * H + head] = ps;
                adst[gr * H + head] = pd;
            }
        }
    }
}

// ---------------- CSR build ----------------
__global__ __launch_bounds__(256) void count_deg(const int* __restrict__ ei, int E_, int N_,
                                                 int* __restrict__ deg) {
    int eid = blockIdx.x * 256 + threadIdx.x;
    int Etot = E_ + N_;
    if (eid >= Etot) return;
    int dst = (eid < E_) ? ei[E_ + eid] : (eid - E_);
    atomicAdd(&deg[dst], 1);
}

__global__ __launch_bounds__(1024) void scan_offsets(const int* __restrict__ deg,
                                                     int* __restrict__ off, int n) {
    __shared__ int wsum[16];
    int tid = threadIdx.x;
    int lane = tid & 63, w = tid >> 6;
    int chunk = (n + 1023) / 1024;
    int b = tid * chunk;
    int e = min(b + chunk, n);
    int s = 0;
    for (int i = b; i < e; ++i) s += deg[i];
    int v = s;
    #pragma unroll
    for (int o = 1; o < 64; o <<= 1) {
        int t = __shfl_up(v, o);
        if (lane >= o) v += t;
    }
    if (lane == 63) wsum[w] = v;
    __syncthreads();
    if (w == 0) {
        int t = (lane < 16) ? wsum[lane] : 0;
        #pragma unroll
        for (int o = 1; o < 16; o <<= 1) {
            int u = __shfl_up(t, o);
            if (lane >= o) t += u;
        }
        if (lane < 16) wsum[lane] = t;
    }
    __syncthreads();
    int acc = (w > 0 ? wsum[w - 1] : 0) + (v - s);
    for (int i = b; i < e; ++i) { off[i] = acc; acc += deg[i]; }
    if (e == n) off[n] = acc;
}

__global__ __launch_bounds__(256) void scatter_edges(const int* __restrict__ ei, int E_, int N_,
                                                     int* __restrict__ off,
                                                     int* __restrict__ csr) {
    int eid = blockIdx.x * 256 + threadIdx.x;
    int Etot = E_ + N_;
    if (eid >= Etot) return;
    int src, dst;
    if (eid < E_) { src = ei[eid]; dst = ei[E_ + eid]; }
    else          { src = dst = eid - E_; }
    int pos = atomicAdd(&off[dst], 1);
    csr[pos] = src;
}

// ---------------- fused GAT aggregation, 4 heads (wave/node; LDS-staged softmax) ----------------
// Lane j computes edge j's scores/exp ONCE (vs wave-redundant), stages w,u in LDS;
// the serial gather loop is then 4 FMA + 4 loads + 5 LDS broadcasts per edge.
__global__ __launch_bounds__(256) void gat_agg_h4(const int* __restrict__ off,
                                                  const int* __restrict__ csr,
                                                  const float* __restrict__ asrc,
                                                  const float* __restrict__ adst,
                                                  const float* __restrict__ hsrc,
                                                  const float* __restrict__ bias,
                                                  float* __restrict__ outp, int N_) {
    __shared__ float wls[4][256];   // [wave][head*64 + slot]
    __shared__ int   uls[4][64];
    int wv = threadIdx.x >> 6, lane = threadIdx.x & 63;
    int node = blockIdx.x * 4 + wv;
    if (node >= N_) return;
    int s = node ? off[node - 1] : 0;
    int e = off[node];
    int deg = e - s;
    float4 ad = *(const float4*)(adst + node * 4);
    float* wl = wls[wv];
    int*   ul = uls[wv];
    float a0 = 0.f, a1 = 0.f, a2 = 0.f, a3 = 0.f;
    float d0 = 0.f, d1 = 0.f, d2 = 0.f, d3 = 0.f;

    if (deg <= 64) {
        // ---- fast path: scores stay in registers between max and exp ----
        float e0 = -INFINITY, e1 = -INFINITY, e2 = -INFINITY, e3 = -INFINITY;
        int u = 0;
        if (lane < deg) {
            u = csr[s + lane];
            float4 as = *(const float4*)(asrc + u * 4);
            e0 = as.x + ad.x; e0 = e0 > 0.f ? e0 : LEAKY * e0;
            e1 = as.y + ad.y; e1 = e1 > 0.f ? e1 : LEAKY * e1;
            e2 = as.z + ad.z; e2 = e2 > 0.f ? e2 : LEAKY * e2;
            e3 = as.w + ad.w; e3 = e3 > 0.f ? e3 : LEAKY * e3;
        }
        float m0 = e0, m1 = e1, m2 = e2, m3 = e3;
        #pragma unroll
        for (int o = 32; o > 0; o >>= 1) {
            m0 = fmaxf(m0, __shfl_xor(m0, o));
            m1 = fmaxf(m1, __shfl_xor(m1, o));
            m2 = fmaxf(m2, __shfl_xor(m2, o));
            m3 = fmaxf(m3, __shfl_xor(m3, o));
        }
        if (lane < deg) {
            float w0 = __expf(e0 - m0), w1 = __expf(e1 - m1);
            float w2 = __expf(e2 - m2), w3 = __expf(e3 - m3);
            d0 = w0; d1 = w1; d2 = w2; d3 = w3;
            wl[lane] = w0; wl[64 + lane] = w1; wl[128 + lane] = w2; wl[192 + lane] = w3;
            ul[lane] = u;
        }
        int j = 0;
        for (; j + 2 <= deg; j += 2) {
            int u0 = ul[j], u1 = ul[j + 1];
            float W00 = wl[j],     W01 = wl[64 + j],     W02 = wl[128 + j],     W03 = wl[192 + j];
            float W10 = wl[j + 1], W11 = wl[64 + j + 1], W12 = wl[128 + j + 1], W13 = wl[192 + j + 1];
            const float* hp0 = hsrc + (size_t)u0 * 256 + lane;
            const float* hp1 = hsrc + (size_t)u1 * 256 + lane;
            float g00 = hp0[0], g01 = hp0[64], g02 = hp0[128], g03 = hp0[192];
            float g10 = hp1[0], g11 = hp1[64], g12 = hp1[128], g13 = hp1[192];
            a0 += W00 * g00; a1 += W01 * g01; a2 += W02 * g02; a3 += W03 * g03;
            a0 += W10 * g10; a1 += W11 * g11; a2 += W12 * g12; a3 += W13 * g13;
        }
        if (j < deg) {
            int u0 = ul[j];
            const float* hp = hsrc + (size_t)u0 * 256 + lane;
            a0 += wl[j] * hp[0];
            a1 += wl[64 + j] * hp[64];
            a2 += wl[128 + j] * hp[128];
            a3 += wl[192 + j] * hp[192];
        }
    } else {
        // ---- general path: strided max, then 64-edge chunks with recompute ----
        float m0 = -INFINITY, m1 = -INFINITY, m2 = -INFINITY, m3 = -INFINITY;
        for (int i = s + lane; i < e; i += 64) {
            int u = csr[i];
            float4 as = *(const float4*)(asrc + u * 4);
            float t;
            t = as.x + ad.x; t = t > 0.f ? t : LEAKY * t; m0 = fmaxf(m0, t);
            t = as.y + ad.y; t = t > 0.f ? t : LEAKY * t; m1 = fmaxf(m1, t);
            t = as.z + ad.z; t = t > 0.f ? t : LEAKY * t; m2 = fmaxf(m2, t);
            t = as.w + ad.w; t = t > 0.f ? t : LEAKY * t; m3 = fmaxf(m3, t);
        }
        #pragma unroll
        for (int o = 32; o > 0; o >>= 1) {
            m0 = fmaxf(m0, __shfl_xor(m0, o));
            m1 = fmaxf(m1, __shfl_xor(m1, o));
            m2 = fmaxf(m2, __shfl_xor(m2, o));
            m3 = fmaxf(m3, __shfl_xor(m3, o));
        }
        for (int base = s; base < e; base += 64) {
            int cnt = min(64, e - base);
            if (lane < cnt) {
                int u = csr[base + lane];
                float4 as = *(const float4*)(asrc + u * 4);
                float t, w;
                t = as.x + ad.x; t = t > 0.f ? t : LEAKY * t; w = __expf(t - m0); d0 += w; wl[lane] = w;
                t = as.y + ad.y; t = t > 0.f ? t : LEAKY * t; w = __expf(t - m1); d1 += w; wl[64 + lane] = w;
                t = as.z + ad.z; t = t > 0.f ? t : LEAKY * t; w = __expf(t - m2); d2 += w; wl[128 + lane] = w;
                t = as.w + ad.w; t = t > 0.f ? t : LEAKY * t; w = __expf(t - m3); d3 += w; wl[192 + lane] = w;
                ul[lane] = u;
            }
            for (int j = 0; j < cnt; ++j) {
                int u0 = ul[j];
                const float* hp = hsrc + (size_t)u0 * 256 + lane;
                a0 += wl[j] * hp[0];
                a1 += wl[64 + j] * hp[64];
                a2 += wl[128 + j] * hp[128];
                a3 += wl[192 + j] * hp[192];
            }
        }
    }
    // denom tree-sum across lanes (inactive lanes contributed 0)
    #pragma unroll
    for (int o = 32; o > 0; o >>= 1) {
        d0 += __shfl_xor(d0, o);
        d1 += __shfl_xor(d1, o);
        d2 += __shfl_xor(d2, o);
        d3 += __shfl_xor(d3, o);
    }
    size_t ob = (size_t)node * 256 + lane;
    float v;
    v = a0 / (d0 + 1e-16f) + bias[lane];       outp[ob]       = v > 0.f ? v : expm1f(v);
    v = a1 / (d1 + 1e-16f) + bias[lane + 64];  outp[ob + 64]  = v > 0.f ? v : expm1f(v);
    v = a2 / (d2 + 1e-16f) + bias[lane + 128]; outp[ob + 128] = v > 0.f ? v : expm1f(v);
    v = a3 / (d3 + 1e-16f) + bias[lane + 192]; outp[ob + 192] = v > 0.f ? v : expm1f(v);
}

// ---------------- fused GAT aggregation, 1 head (wave/node; LDS-staged softmax) ----------------
__global__ __launch_bounds__(256) void gat_agg_h1(const int* __restrict__ off,
                                                  const int* __restrict__ csr,
                                                  const float* __restrict__ asrc,
                                                  const float* __restrict__ adst,
                                                  const float* __restrict__ g,
                                                  const float* __restrict__ bias,
                                                  float* __restrict__ outp, int N_) {
    __shared__ float wls[4][64];
    __shared__ int   uls[4][64];
    int wv = threadIdx.x >> 6, lane = threadIdx.x & 63;
    int node = blockIdx.x * 4 + wv;
    if (node >= N_) return;
    int s = node ? off[node - 1] : 0;
    int e = off[node];
    int deg = e - s;
    float ad = adst[node];
    float* wl = wls[wv];
    int*   ul = uls[wv];
    float a = 0.f, d = 0.f;

    if (deg <= 64) {
        float ev = -INFINITY;
        int u = 0;
        if (lane < deg) {
            u = csr[s + lane];
            ev = asrc[u] + ad;
            ev = ev > 0.f ? ev : LEAKY * ev;
        }
        float mm = ev;
        #pragma unroll
        for (int o = 32; o > 0; o >>= 1) mm = fmaxf(mm, __shfl_xor(mm, o));
        if (lane < deg) {
            float w = __expf(ev - mm);
            d = w;
            wl[lane] = w;
            ul[lane] = u;
        }
        int j = 0;
        for (; j + 4 <= deg; j += 4) {
            int u0 = ul[j], u1 = ul[j + 1], u2 = ul[j + 2], u3 = ul[j + 3];
            float W0 = wl[j], W1 = wl[j + 1], W2 = wl[j + 2], W3 = wl[j + 3];
            float g0 = g[(size_t)u0 * 64 + lane];
            float g1 = g[(size_t)u1 * 64 + lane];
            float g2 = g[(size_t)u2 * 64 + lane];
            float g3 = g[(size_t)u3 * 64 + lane];
            a += W0 * g0; a += W1 * g1; a += W2 * g2; a += W3 * g3;
        }
        for (; j < deg; ++j) {
            a += wl[j] * g[(size_t)ul[j] * 64 + lane];
        }
    } else {
        float mm = -INFINITY;
        for (int i = s + lane; i < e; i += 64) {
            float t = asrc[csr[i]] + ad;
            t = t > 0.f ? t : LEAKY * t;
            mm = fmaxf(mm, t);
        }
        #pragma unroll
        for (int o = 32; o > 0; o >>= 1) mm = fmaxf(mm, __shfl_xor(mm, o));
        for (int base = s; base < e; base += 64) {
            int cnt = min(64, e - base);
            if (lane < cnt) {
                int u = csr[base + lane];
                float t = asrc[u] + ad;
                t = t > 0.f ? t : LEAKY * t;
                float w = __expf(t - mm);
                d += w;
                wl[lane] = w;
                ul[lane] = u;
            }
            for (int j = 0; j < cnt; ++j)
                a += wl[j] * g[(size_t)ul[j] * 64 + lane];
        }
    }
    #pragma unroll
    for (int o = 32; o > 0; o >>= 1) d += __shfl_xor(d, o);
    float v = a / (d + 1e-16f) + bias[lane];
    outp[(size_t)node * 64 + lane] = v > 0.f ? v : expm1f(v);
}

extern "C" void kernel_launch(void* const* d_in, const int* in_sizes, int n_in,
                              void* d_out, int out_size, void* d_ws, size_t ws_size,
                              hipStream_t stream) {
    const float* x        = (const float*)d_in[0];
    const int*   ei       = (const int*)d_in[1];     // int32 (harness: integer -> const int*)
    // d_in[2] = edge_attr (unused: PyG GATConv with edge_dim=None)
    const float* W1       = (const float*)d_in[3];
    const float* att_src1 = (const float*)d_in[4];
    const float* att_dst1 = (const float*)d_in[5];
    const float* b1       = (const float*)d_in[6];
    const float* W2       = (const float*)d_in[7];
    const float* att_src2 = (const float*)d_in[8];
    const float* att_dst2 = (const float*)d_in[9];
    const float* b2       = (const float*)d_in[10];
    float* out = (float*)d_out;

    const int N = in_sizes[0] / 128;     // 50000
    const int E = in_sizes[1] / 2;       // 800000
    const int Etot = E + N;

    float* ws    = (float*)d_ws;
    float* h1    = ws;                         // N*256  (L1 GEMM out; dead after gat_agg_h4)
    float* h2    = h1 + (size_t)N * 256;       // N*256  (L1 out = L2 GEMM in)
    float* g2    = h1;                         // N*64   (aliases h1 — dead by then)
    float* asrc1 = h2 + (size_t)N * 256;       // N*4
    float* adst1 = asrc1 + (size_t)N * 4;      // N*4
    float* asrc2 = adst1 + (size_t)N * 4;      // N
    float* adst2 = asrc2 + N;                  // N
    int*   deg   = (int*)(adst2 + N);          // N+1
    int*   off   = deg + (N + 1);              // N+1 (scan out; scatter cursor; bucket ends)
    int*   csr   = off + (N + 1);              // Etot

    // ---- CSR build (graph identical for both layers) ----
    hipMemsetAsync(deg, 0, (N + 1) * sizeof(int), stream);
    count_deg<<<(Etot + 255) / 256, 256, 0, stream>>>(ei, E, N, deg);
    scan_offsets<<<1, 1024, 0, stream>>>(deg, off, N);
    scatter_edges<<<(Etot + 255) / 256, 256, 0, stream>>>(ei, E, N, off, csr);

    // ---- layer 1 ----
    {
        dim3 g((N + BM - 1) / BM, 256 / BN);
        gemm_att<<<g, 256, 0, stream>>>(x, W1, h1, att_src1, att_dst1, asrc1, adst1, N, 128, 256);
    }
    gat_agg_h4<<<(N + 3) / 4, 256, 0, stream>>>(off, csr, asrc1, adst1, h1, b1, h2, N);

    // ---- layer 2 ----
    {
        dim3 g((N + BM - 1) / BM, 64 / BN);
        gemm_att<<<g, 256, 0, stream>>>(h2, W2, g2, att_src2, att_dst2, asrc2, adst2, N, 256, 64);
    }
    gat_agg_h1<<<(N + 3) / 4, 256, 0, stream>>>(off, csr, asrc2, adst2, g2, b2, out, N);
}